// Round 4
// baseline (914.630 us; speedup 1.0000x reference)
//
#include <hip/hip_runtime.h>
#include <hip/hip_bf16.h>
#include <math.h>

#define HIDDEN 1024
#define NHEADS 16
#define DK 64
#define DFF 4096
#define SEQ 2048
#define NBATCH 4
#define NTOK (NBATCH*SEQ)

typedef __attribute__((ext_vector_type(8))) short bf16x8;
typedef __attribute__((ext_vector_type(4))) float f32x4;
typedef __attribute__((ext_vector_type(4))) unsigned short us4;

typedef __attribute__((address_space(1))) void gvoid;
typedef __attribute__((address_space(3))) void lvoid;

// fp32 -> bf16, round-to-nearest-even
__device__ __forceinline__ unsigned short f2b(float f) {
  union { float f; unsigned int u; } v; v.f = f;
  unsigned int u = v.u;
  return (unsigned short)((u + 0x7fffu + ((u >> 16) & 1u)) >> 16);
}

__device__ __forceinline__ void gload_lds16(const void* g, void* l) {
  __builtin_amdgcn_global_load_lds((gvoid*)g, (lvoid*)l, 16, 0, 0);
}

// ---------------- fp32 -> bf16 elementwise ----------------
__global__ void k_cvt(const float* __restrict__ in, unsigned short* __restrict__ out, int n4) {
  int i = blockIdx.x * blockDim.x + threadIdx.x;
  int stride = gridDim.x * blockDim.x;
  for (; i < n4; i += stride) {
    float4 v = ((const float4*)in)[i];
    us4 o;
    o.x = f2b(v.x); o.y = f2b(v.y); o.z = f2b(v.z); o.w = f2b(v.w);
    ((us4*)out)[i] = o;
  }
}

// ---------------- weight convert + transpose: W[K][N] f32 -> WT[N][K] bf16 ----------------
__global__ void k_transcvt(const float* __restrict__ W, unsigned short* __restrict__ WT,
                           int K, int N) {
  __shared__ unsigned short tile[64][80];
  int t = threadIdx.x;
  int k0 = blockIdx.x * 64, n0 = blockIdx.y * 64;
  int lr = t >> 2, c0 = (t & 3) * 16;
  const float* src = W + (size_t)(k0 + lr) * N + n0 + c0;
  #pragma unroll
  for (int j = 0; j < 16; ++j) tile[lr][c0 + j] = f2b(src[j]);
  __syncthreads();
  unsigned short* dst = WT + (size_t)(n0 + lr) * K + k0 + c0;
  #pragma unroll
  for (int j = 0; j < 16; ++j) dst[j] = tile[c0 + j][lr];
}

// ---------------- V[b,h,s,d] -> VT[b,h,d,s] (bf16) ----------------
__global__ void k_vtrans(const unsigned short* __restrict__ V, unsigned short* __restrict__ VT) {
  __shared__ unsigned short tile[64][80];
  int bid = blockIdx.x;
  int st = bid & 31, bh = bid >> 5;
  int s0 = st * 64;
  int t = threadIdx.x;
  int lr = t >> 2, c0 = (t & 3) * 16;
  const unsigned short* src = V + (size_t)bh * SEQ * DK + (size_t)(s0 + lr) * DK + c0;
  #pragma unroll
  for (int j = 0; j < 16; ++j) tile[lr][c0 + j] = src[j];
  __syncthreads();
  unsigned short* dst = VT + (size_t)bh * DK * SEQ + (size_t)lr * SEQ + s0 + c0;
  #pragma unroll
  for (int j = 0; j < 16; ++j) dst[j] = tile[c0 + j][lr];
}

// ---------------- GEMM: C[M][N] = A[M][K] @ Bt[N][K]^T + bias ----------------
// MODE 0: QKV scatter -> [b,h,s,d] bf16   MODE 1: dense fp32   MODE 2: GELU, dense bf16
template <int MODE>
__global__ __launch_bounds__(256)
void k_gemm(const unsigned short* __restrict__ A, const unsigned short* __restrict__ Bt,
            const float* __restrict__ bias, void* __restrict__ Cout,
            int M, int N, int K) {
  __shared__ __align__(1024) char lds[32768];  // A tile 16KB | B tile 16KB
  const int tid = threadIdx.x;
  const int lane = tid & 63;
  const int wid = tid >> 6;
  const int wm = wid >> 1, wn = wid & 1;
  const int l15 = lane & 15, lg = lane >> 4;
  const int bm = blockIdx.x, bn = blockIdx.y;

  f32x4 acc[4][4] = {};

  const char* Ab = (const char*)A + (size_t)bm * 128 * (size_t)K * 2;
  const char* Bb = (const char*)Bt + (size_t)bn * 128 * (size_t)K * 2;
  const size_t ldr = (size_t)K * 2;

  for (int k0 = 0; k0 < K; k0 += 64) {
    #pragma unroll
    for (int r = 0; r < 4; ++r) {
      int li = tid * 16 + r * 4096;
      int row = li >> 7;
      int col = (li & 127) ^ ((row & 7) << 4);  // inverse-swizzled global source
      gload_lds16(Ab + (size_t)row * ldr + k0 * 2 + col, lds + li);
      gload_lds16(Bb + (size_t)row * ldr + k0 * 2 + col, lds + 16384 + li);
    }
    __syncthreads();
    #pragma unroll
    for (int kc = 0; kc < 2; ++kc) {
      bf16x8 af[4], bfr[4];
      #pragma unroll
      for (int i = 0; i < 4; ++i) {
        int kb = kc * 64 + (lg << 4);
        int lr = wm * 64 + i * 16 + l15;
        af[i] = *(const bf16x8*)(lds + lr * 128 + (kb ^ ((lr & 7) << 4)));
        int lr2 = wn * 64 + i * 16 + l15;
        bfr[i] = *(const bf16x8*)(lds + 16384 + lr2 * 128 + (kb ^ ((lr2 & 7) << 4)));
      }
      #pragma unroll
      for (int mi = 0; mi < 4; ++mi)
        #pragma unroll
        for (int ni = 0; ni < 4; ++ni)
          acc[mi][ni] = __builtin_amdgcn_mfma_f32_16x16x32_bf16(af[mi], bfr[ni], acc[mi][ni], 0, 0, 0);
    }
    __syncthreads();
  }

  const int mbase = bm * 128 + wm * 64;
  const int nbase = bn * 128 + wn * 64;
  #pragma unroll
  for (int ni = 0; ni < 4; ++ni) {
    int n = nbase + ni * 16 + l15;
    float bv = bias[n];
    #pragma unroll
    for (int mi = 0; mi < 4; ++mi) {
      #pragma unroll
      for (int r = 0; r < 4; ++r) {
        int m = mbase + mi * 16 + lg * 4 + r;
        float val = acc[mi][ni][r] + bv;
        if (MODE == 0) {
          int b = m >> 11, s = m & 2047;
          int h = n >> 6, d = n & 63;
          ((unsigned short*)Cout)[((size_t)(b * NHEADS + h) * SEQ + s) * DK + d] = f2b(val);
        } else if (MODE == 1) {
          ((float*)Cout)[(size_t)m * N + n] = val;
        } else {
          float x = val;
          float t = tanhf(0.7978845608028654f * (x + 0.044715f * x * x * x));
          ((unsigned short*)Cout)[(size_t)m * N + n] = f2b(0.5f * x * (1.0f + t));
        }
      }
    }
  }
}

// ---------------- flash attention ----------------
// grid: (B*H) * (S/64); 4 waves, each wave owns 16 q-rows. d_k=64.
__global__ __launch_bounds__(256)
void k_attn(const unsigned short* __restrict__ Qp, const unsigned short* __restrict__ Kp,
            const unsigned short* __restrict__ VTp, unsigned short* __restrict__ ctx) {
  const int tid = threadIdx.x, w = tid >> 6, lane = tid & 63;
  const int l15 = lane & 15, lg = lane >> 4;
  const int bid = blockIdx.x;
  const int qb = bid & 31, bh = bid >> 5;
  const size_t base = (size_t)bh * SEQ * DK;
  const size_t baseT = (size_t)bh * DK * SEQ;
  const int q0 = qb * 64 + w * 16;

  __shared__ __align__(1024) char pl_all[4][2048];
  char* pl = pl_all[w];

  bf16x8 qf[2];
  #pragma unroll
  for (int kc = 0; kc < 2; ++kc)
    qf[kc] = *(const bf16x8*)(Qp + base + (size_t)(q0 + l15) * DK + kc * 32 + lg * 8);

  float m_run[4], l_run[4];
  f32x4 cacc[4] = {};
  #pragma unroll
  for (int r = 0; r < 4; ++r) { m_run[r] = -1e30f; l_run[r] = 0.f; }

  for (int kv0 = 0; kv0 < SEQ; kv0 += 64) {
    f32x4 s[4] = {};
    #pragma unroll
    for (int ct = 0; ct < 4; ++ct) {
      #pragma unroll
      for (int kc = 0; kc < 2; ++kc) {
        bf16x8 kf = *(const bf16x8*)(Kp + base + (size_t)(kv0 + ct * 16 + l15) * DK + kc * 32 + lg * 8);
        s[ct] = __builtin_amdgcn_mfma_f32_16x16x32_bf16(qf[kc], kf, s[ct], 0, 0, 0);
      }
    }
    float p[4][4];
    #pragma unroll
    for (int r = 0; r < 4; ++r) {
      float mx = fmaxf(fmaxf(s[0][r], s[1][r]), fmaxf(s[2][r], s[3][r]));
      #pragma unroll
      for (int d = 1; d < 16; d <<= 1) mx = fmaxf(mx, __shfl_xor(mx, d));
      float tmax = mx * 0.125f;
      float mnew = fmaxf(m_run[r], tmax);
      float corr = __expf(m_run[r] - mnew);
      float sum = 0.f;
      #pragma unroll
      for (int ct = 0; ct < 4; ++ct) {
        float pv = __expf(s[ct][r] * 0.125f - mnew);
        p[ct][r] = pv; sum += pv;
      }
      #pragma unroll
      for (int d = 1; d < 16; d <<= 1) sum += __shfl_xor(sum, d);
      l_run[r] = l_run[r] * corr + sum;
      m_run[r] = mnew;
      #pragma unroll
      for (int dt = 0; dt < 4; ++dt) cacc[dt][r] *= corr;
    }
    // P -> LDS (bf16, XOR-swizzled rows)
    #pragma unroll
    for (int ct = 0; ct < 4; ++ct)
      #pragma unroll
      for (int r = 0; r < 4; ++r) {
        int pr = lg * 4 + r;
        int cb = (ct * 16 + l15) * 2;
        *(unsigned short*)(pl + pr * 128 + (cb ^ ((pr & 7) << 4))) = f2b(p[ct][r]);
      }
    // PV
    #pragma unroll
    for (int kc = 0; kc < 2; ++kc) {
      int kb = kc * 64 + (lg << 4);
      bf16x8 pf = *(const bf16x8*)(pl + l15 * 128 + (kb ^ ((l15 & 7) << 4)));
      #pragma unroll
      for (int dt = 0; dt < 4; ++dt) {
        bf16x8 vf = *(const bf16x8*)(VTp + baseT + (size_t)(dt * 16 + l15) * SEQ + kv0 + kc * 32 + lg * 8);
        cacc[dt] = __builtin_amdgcn_mfma_f32_16x16x32_bf16(pf, vf, cacc[dt], 0, 0, 0);
      }
    }
  }
  const int b = bh >> 4, h = bh & 15;
  #pragma unroll
  for (int r = 0; r < 4; ++r) {
    float inv = 1.f / l_run[r];
    int qg = q0 + lg * 4 + r;
    size_t rowbase = ((size_t)(b * SEQ + qg)) * HIDDEN + h * 64;
    #pragma unroll
    for (int dt = 0; dt < 4; ++dt)
      ctx[rowbase + dt * 16 + l15] = f2b(cacc[dt][r] * inv);
  }
}

// ---------------- residual + LayerNorm ----------------
__global__ __launch_bounds__(256)
void k_ln(const float* __restrict__ a, const float* __restrict__ b,
          const float* __restrict__ gamma, const float* __restrict__ beta,
          float* __restrict__ outf, unsigned short* __restrict__ outb) {
  int row = blockIdx.x;
  int tid = threadIdx.x;
  const float4* A = (const float4*)(a + (size_t)row * HIDDEN);
  const float4* B = (const float4*)(b + (size_t)row * HIDDEN);
  float4 va = A[tid], vb = B[tid];
  float x0 = va.x + vb.x, x1 = va.y + vb.y, x2 = va.z + vb.z, x3 = va.w + vb.w;
  float sum = x0 + x1 + x2 + x3;
  float sq = x0 * x0 + x1 * x1 + x2 * x2 + x3 * x3;
  #pragma unroll
  for (int d = 1; d < 64; d <<= 1) { sum += __shfl_xor(sum, d); sq += __shfl_xor(sq, d); }
  __shared__ float red[8];
  if ((tid & 63) == 0) { red[(tid >> 6) * 2] = sum; red[(tid >> 6) * 2 + 1] = sq; }
  __syncthreads();
  sum = red[0] + red[2] + red[4] + red[6];
  sq  = red[1] + red[3] + red[5] + red[7];
  float mu = sum * (1.f / HIDDEN);
  float var = sq * (1.f / HIDDEN) - mu * mu;
  float rs = rsqrtf(var + 1e-5f);
  float4 g = ((const float4*)gamma)[tid];
  float4 be = ((const float4*)beta)[tid];
  float y0 = (x0 - mu) * rs * g.x + be.x;
  float y1 = (x1 - mu) * rs * g.y + be.y;
  float y2 = (x2 - mu) * rs * g.z + be.z;
  float y3 = (x3 - mu) * rs * g.w + be.w;
  if (outf) { float4 o; o.x = y0; o.y = y1; o.z = y2; o.w = y3; ((float4*)(outf + (size_t)row * HIDDEN))[tid] = o; }
  if (outb) { us4 o; o.x = f2b(y0); o.y = f2b(y1); o.z = f2b(y2); o.w = f2b(y3); ((us4*)(outb + (size_t)row * HIDDEN))[tid] = o; }
}

// ---------------- workspace layout (bytes) ----------------
// total required: 176,160,768 (168 MiB)
#define OFF_XB   ((size_t)0)            // x bf16 (16.78MB); reused as ln1_bf16
#define OFF_WQT  ((size_t)16777216)
#define OFF_WKT  ((size_t)18874368)
#define OFF_WVT  ((size_t)20971520)
#define OFF_WOT  ((size_t)23068672)
#define OFF_W1T  ((size_t)25165824)
#define OFF_W2T  ((size_t)33554432)
#define OFF_Q    ((size_t)41943040)     // Q; later overlaid by ff1 (spans Q..VT)
#define OFF_K    ((size_t)58720256)
#define OFF_V    ((size_t)75497472)     // V; reused as ctx
#define OFF_VT   ((size_t)92274688)
#define OFF_AO   ((size_t)109051904)    // attn proj out f32; reused as ff2 f32
#define OFF_LN1F ((size_t)142606336)

extern "C" void kernel_launch(void* const* d_in, const int* in_sizes, int n_in,
                              void* d_out, int out_size, void* d_ws, size_t ws_size,
                              hipStream_t stream) {
  const float* x   = (const float*)d_in[0];
  const float* Wq  = (const float*)d_in[1];
  const float* bq  = (const float*)d_in[2];
  const float* Wk  = (const float*)d_in[3];
  const float* bk  = (const float*)d_in[4];
  const float* Wv  = (const float*)d_in[5];
  const float* bv  = (const float*)d_in[6];
  const float* Wo  = (const float*)d_in[7];
  const float* bo  = (const float*)d_in[8];
  const float* W1  = (const float*)d_in[9];
  const float* b1  = (const float*)d_in[10];
  const float* W2  = (const float*)d_in[11];
  const float* b2  = (const float*)d_in[12];
  const float* g1  = (const float*)d_in[13];
  const float* be1 = (const float*)d_in[14];
  const float* g2  = (const float*)d_in[15];
  const float* be2 = (const float*)d_in[16];

  char* ws = (char*)d_ws;
  unsigned short* xb   = (unsigned short*)(ws + OFF_XB);
  unsigned short* wqT  = (unsigned short*)(ws + OFF_WQT);
  unsigned short* wkT  = (unsigned short*)(ws + OFF_WKT);
  unsigned short* wvT  = (unsigned short*)(ws + OFF_WVT);
  unsigned short* woT  = (unsigned short*)(ws + OFF_WOT);
  unsigned short* w1T  = (unsigned short*)(ws + OFF_W1T);
  unsigned short* w2T  = (unsigned short*)(ws + OFF_W2T);
  unsigned short* Qb   = (unsigned short*)(ws + OFF_Q);
  unsigned short* Kb   = (unsigned short*)(ws + OFF_K);
  unsigned short* Vb   = (unsigned short*)(ws + OFF_V);
  unsigned short* VTb  = (unsigned short*)(ws + OFF_VT);
  unsigned short* ctx  = (unsigned short*)(ws + OFF_V);    // reuse V
  float*          ao   = (float*)(ws + OFF_AO);
  float*          ln1f = (float*)(ws + OFF_LN1F);
  unsigned short* ln1b = (unsigned short*)(ws + OFF_XB);   // reuse xb
  unsigned short* ff1  = (unsigned short*)(ws + OFF_Q);    // reuse Q..VT span
  float*          ff2  = (float*)(ws + OFF_AO);            // reuse ao

  // 1. x -> bf16
  k_cvt<<<2048, 256, 0, stream>>>(x, xb, NTOK * HIDDEN / 4);

  // 2. weight transposes
  k_transcvt<<<dim3(16, 16), 256, 0, stream>>>(Wq, wqT, 1024, 1024);
  k_transcvt<<<dim3(16, 16), 256, 0, stream>>>(Wk, wkT, 1024, 1024);
  k_transcvt<<<dim3(16, 16), 256, 0, stream>>>(Wv, wvT, 1024, 1024);
  k_transcvt<<<dim3(16, 16), 256, 0, stream>>>(Wo, woT, 1024, 1024);
  k_transcvt<<<dim3(16, 64), 256, 0, stream>>>(W1, w1T, 1024, 4096);
  k_transcvt<<<dim3(64, 16), 256, 0, stream>>>(W2, w2T, 4096, 1024);

  // 3. QKV projections (scatter to [b,h,s,d])
  k_gemm<0><<<dim3(64, 8), 256, 0, stream>>>(xb, wqT, bq, Qb, NTOK, HIDDEN, HIDDEN);
  k_gemm<0><<<dim3(64, 8), 256, 0, stream>>>(xb, wkT, bk, Kb, NTOK, HIDDEN, HIDDEN);
  k_gemm<0><<<dim3(64, 8), 256, 0, stream>>>(xb, wvT, bv, Vb, NTOK, HIDDEN, HIDDEN);

  // 4. V -> VT
  k_vtrans<<<2048, 256, 0, stream>>>(Vb, VTb);

  // 5. attention -> ctx [b,s,h*64+d] bf16
  k_attn<<<2048, 256, 0, stream>>>(Qb, Kb, VTb, ctx);

  // 6. output projection -> fp32
  k_gemm<1><<<dim3(64, 8), 256, 0, stream>>>(ctx, woT, bo, ao, NTOK, HIDDEN, HIDDEN);

  // 7. LN1 (x + attn_out)
  k_ln<<<NTOK, 256, 0, stream>>>(x, ao, g1, be1, ln1f, ln1b);

  // 8. FFN1 + GELU -> bf16
  k_gemm<2><<<dim3(64, 32), 256, 0, stream>>>(ln1b, w1T, b1, ff1, NTOK, DFF, HIDDEN);

  // 9. FFN2 -> fp32
  k_gemm<1><<<dim3(64, 8), 256, 0, stream>>>(ff1, w2T, b2, ff2, NTOK, HIDDEN, DFF);

  // 10. LN2 -> d_out
  k_ln<<<NTOK, 256, 0, stream>>>(ln1f, ff2, g2, be2, (float*)d_out, nullptr);
}

// Round 6
// 698.529 us; speedup vs baseline: 1.3094x; 1.3094x over previous
//
#include <hip/hip_runtime.h>
#include <hip/hip_bf16.h>
#include <math.h>

#define HIDDEN 1024
#define NHEADS 16
#define DK 64
#define DFF 4096
#define SEQ 2048
#define NBATCH 4
#define NTOK (NBATCH*SEQ)

typedef __attribute__((ext_vector_type(8))) short bf16x8;
typedef __attribute__((ext_vector_type(4))) float f32x4;
typedef __attribute__((ext_vector_type(16))) float f32x16;
typedef __attribute__((ext_vector_type(4))) unsigned short us4;
typedef __attribute__((ext_vector_type(2))) unsigned int u32x2;

typedef __attribute__((address_space(1))) void gvoid;
typedef __attribute__((address_space(3))) void lvoid;

// fp32 -> bf16, round-to-nearest-even
__device__ __forceinline__ unsigned short f2b(float f) {
  union { float f; unsigned int u; } v; v.f = f;
  unsigned int u = v.u;
  return (unsigned short)((u + 0x7fffu + ((u >> 16) & 1u)) >> 16);
}

// pack two f32 -> one u32 of 2 bf16 (lo in low half), RNE
__device__ __forceinline__ unsigned pack_bf16(float lo, float hi) {
  float2 f2; f2.x = lo; f2.y = hi;
  __hip_bfloat162 h = __float22bfloat162_rn(f2);
  union { __hip_bfloat162 h; unsigned u; } c; c.h = h;
  return c.u;
}

__device__ __forceinline__ void gload_lds16(const void* g, void* l) {
  __builtin_amdgcn_global_load_lds((gvoid*)g, (lvoid*)l, 16, 0, 0);
}

// ---------------- fp32 -> bf16 elementwise ----------------
__global__ void k_cvt(const float* __restrict__ in, unsigned short* __restrict__ out, int n4) {
  int i = blockIdx.x * blockDim.x + threadIdx.x;
  int stride = gridDim.x * blockDim.x;
  for (; i < n4; i += stride) {
    float4 v = ((const float4*)in)[i];
    us4 o;
    o.x = f2b(v.x); o.y = f2b(v.y); o.z = f2b(v.z); o.w = f2b(v.w);
    ((us4*)out)[i] = o;
  }
}

// ---------------- weight convert + transpose: W[K][N] f32 -> WT[N][K] bf16 ----------------
__global__ void k_transcvt(const float* __restrict__ W, unsigned short* __restrict__ WT,
                           int K, int N) {
  __shared__ unsigned short tile[64][80];
  int t = threadIdx.x;
  int k0 = blockIdx.x * 64, n0 = blockIdx.y * 64;
  int lr = t >> 2, c0 = (t & 3) * 16;
  const float* src = W + (size_t)(k0 + lr) * N + n0 + c0;
  #pragma unroll
  for (int j = 0; j < 16; ++j) tile[lr][c0 + j] = f2b(src[j]);
  __syncthreads();
  unsigned short* dst = WT + (size_t)(n0 + lr) * K + k0 + c0;
  #pragma unroll
  for (int j = 0; j < 16; ++j) dst[j] = tile[c0 + j][lr];
}

// ---------------- V[b,h,s,d] -> VT[b,h,d,s] (bf16) ----------------
__global__ void k_vtrans(const unsigned short* __restrict__ V, unsigned short* __restrict__ VT) {
  __shared__ unsigned short tile[64][80];
  int bid = blockIdx.x;
  int st = bid & 31, bh = bid >> 5;
  int s0 = st * 64;
  int t = threadIdx.x;
  int lr = t >> 2, c0 = (t & 3) * 16;
  const unsigned short* src = V + (size_t)bh * SEQ * DK + (size_t)(s0 + lr) * DK + c0;
  #pragma unroll
  for (int j = 0; j < 16; ++j) tile[lr][c0 + j] = src[j];
  __syncthreads();
  unsigned short* dst = VT + (size_t)bh * DK * SEQ + (size_t)lr * SEQ + s0 + c0;
  #pragma unroll
  for (int j = 0; j < 16; ++j) dst[j] = tile[c0 + j][lr];
}

// ---------------- GEMM: C[M][N] = A[M][K] @ Bt[N][K]^T + bias ----------------
// MODE 0: QKV scatter -> [b,h,s,d] bf16   MODE 1: dense fp32   MODE 2: GELU, dense bf16
template <int MODE>
__global__ __launch_bounds__(256)
void k_gemm(const unsigned short* __restrict__ A, const unsigned short* __restrict__ Bt,
            const float* __restrict__ bias, void* __restrict__ Cout,
            int M, int N, int K) {
  __shared__ __align__(1024) char lds[32768];  // A tile 16KB | B tile 16KB
  const int tid = threadIdx.x;
  const int lane = tid & 63;
  const int wid = tid >> 6;
  const int wm = wid >> 1, wn = wid & 1;
  const int l15 = lane & 15, lg = lane >> 4;
  const int bm = blockIdx.x, bn = blockIdx.y;

  f32x4 acc[4][4] = {};

  const char* Ab = (const char*)A + (size_t)bm * 128 * (size_t)K * 2;
  const char* Bb = (const char*)Bt + (size_t)bn * 128 * (size_t)K * 2;
  const size_t ldr = (size_t)K * 2;

  for (int k0 = 0; k0 < K; k0 += 64) {
    #pragma unroll
    for (int r = 0; r < 4; ++r) {
      int li = tid * 16 + r * 4096;
      int row = li >> 7;
      int col = (li & 127) ^ ((row & 7) << 4);  // inverse-swizzled global source
      gload_lds16(Ab + (size_t)row * ldr + k0 * 2 + col, lds + li);
      gload_lds16(Bb + (size_t)row * ldr + k0 * 2 + col, lds + 16384 + li);
    }
    __syncthreads();
    #pragma unroll
    for (int kc = 0; kc < 2; ++kc) {
      bf16x8 af[4], bfr[4];
      #pragma unroll
      for (int i = 0; i < 4; ++i) {
        int kb = kc * 64 + (lg << 4);
        int lr = wm * 64 + i * 16 + l15;
        af[i] = *(const bf16x8*)(lds + lr * 128 + (kb ^ ((lr & 7) << 4)));
        int lr2 = wn * 64 + i * 16 + l15;
        bfr[i] = *(const bf16x8*)(lds + 16384 + lr2 * 128 + (kb ^ ((lr2 & 7) << 4)));
      }
      #pragma unroll
      for (int mi = 0; mi < 4; ++mi)
        #pragma unroll
        for (int ni = 0; ni < 4; ++ni)
          acc[mi][ni] = __builtin_amdgcn_mfma_f32_16x16x32_bf16(af[mi], bfr[ni], acc[mi][ni], 0, 0, 0);
    }
    __syncthreads();
  }

  const int mbase = bm * 128 + wm * 64;
  const int nbase = bn * 128 + wn * 64;
  #pragma unroll
  for (int ni = 0; ni < 4; ++ni) {
    int n = nbase + ni * 16 + l15;
    float bv = bias[n];
    #pragma unroll
    for (int mi = 0; mi < 4; ++mi) {
      #pragma unroll
      for (int r = 0; r < 4; ++r) {
        int m = mbase + mi * 16 + lg * 4 + r;
        float val = acc[mi][ni][r] + bv;
        if (MODE == 0) {
          int b = m >> 11, s = m & 2047;
          int h = n >> 6, d = n & 63;
          ((unsigned short*)Cout)[((size_t)(b * NHEADS + h) * SEQ + s) * DK + d] = f2b(val);
        } else if (MODE == 1) {
          ((float*)Cout)[(size_t)m * N + n] = val;
        } else {
          float x = val;
          float t = tanhf(0.7978845608028654f * (x + 0.044715f * x * x * x));
          ((unsigned short*)Cout)[(size_t)m * N + n] = f2b(0.5f * x * (1.0f + t));
        }
      }
    }
  }
}

// ---------------- flash attention, swapped-QK^T 32x32 (T12 structure) ----------------
// grid: (B*H=64) * (S/128=16) blocks; 4 waves, each wave owns 32 q-rows.
// Lane owns q = lane&31 (col of S^T / O^T); hi = lane>>5 selects k/d half-sets.
// S^T = mfma(K_frag, Q_frag): lane holds 16 k-values of its q-row -> softmax is
// 15 local ops + one shfl_xor(32). P->bf16 B-frags via cvt_pk + permlane32_swap:
//   permlane32_swap(a,b) -> ret.x = {lo: a_lo, hi: b_lo}; ret.y = {lo: a_hi, hi: b_hi}
//   (odd row of first operand <-> even row of second). word0/2 = swap(w0,w2).x/.y
// O^T accumulated via mfma(VT_frag, P_frag). No LDS, no P round-trip.
__global__ __launch_bounds__(256)
void k_attn(const unsigned short* __restrict__ Qp, const unsigned short* __restrict__ Kp,
            const unsigned short* __restrict__ VTp, unsigned short* __restrict__ ctx) {
  const int tid = threadIdx.x, w = tid >> 6, lane = tid & 63;
  const int l31 = lane & 31, hi = lane >> 5;
  const int bid = blockIdx.x;
  const int qb = bid & 15, bh = bid >> 4;
  const size_t base = (size_t)bh * SEQ * DK;
  const size_t baseT = (size_t)bh * DK * SEQ;
  const int q0 = qb * 128 + w * 32;

  // Q B-fragments: 4 dk-slices of 16
  bf16x8 qf[4];
  #pragma unroll
  for (int sl = 0; sl < 4; ++sl)
    qf[sl] = *(const bf16x8*)(Qp + base + (size_t)(q0 + l31) * DK + sl * 16 + hi * 8);

  // K register double-buffer: prefetch tile 0
  bf16x8 kf[4];
  #pragma unroll
  for (int sl = 0; sl < 4; ++sl)
    kf[sl] = *(const bf16x8*)(Kp + base + (size_t)l31 * DK + sl * 16 + hi * 8);

  float m_run = -1e30f, l_run = 0.f;
  f32x16 o0 = {}, o1 = {};

  for (int kv0 = 0; kv0 < SEQ; kv0 += 32) {
    // QK^T: S^T tile (32k x 32q), dk=64 = 4 slices
    f32x16 s = {};
    #pragma unroll
    for (int sl = 0; sl < 4; ++sl)
      s = __builtin_amdgcn_mfma_f32_32x32x16_bf16(kf[sl], qf[sl], s, 0, 0, 0);

    // prefetch next K tile (hidden under softmax+PV)
    int kvn = kv0 + 32;
    if (kvn < SEQ) {
      #pragma unroll
      for (int sl = 0; sl < 4; ++sl)
        kf[sl] = *(const bf16x8*)(Kp + base + (size_t)(kvn + l31) * DK + sl * 16 + hi * 8);
    }
    // V A-fragments for this tile (issued early; consumed after softmax)
    bf16x8 vf00 = *(const bf16x8*)(VTp + baseT + (size_t)(l31) * SEQ + kv0 + hi * 8);
    bf16x8 vf01 = *(const bf16x8*)(VTp + baseT + (size_t)(l31) * SEQ + kv0 + 16 + hi * 8);
    bf16x8 vf10 = *(const bf16x8*)(VTp + baseT + (size_t)(32 + l31) * SEQ + kv0 + hi * 8);
    bf16x8 vf11 = *(const bf16x8*)(VTp + baseT + (size_t)(32 + l31) * SEQ + kv0 + 16 + hi * 8);

    // online softmax: lane owns q=l31; 16 k-values in s (reg r -> k=(r&3)+8*(r>>2)+4*hi)
    float mx = fmaxf(s[0], s[1]);
    #pragma unroll
    for (int r = 2; r < 16; ++r) mx = fmaxf(mx, s[r]);
    mx = fmaxf(mx, __shfl_xor(mx, 32));
    float mnew = fmaxf(m_run, mx * 0.125f);
    float corr = __expf(m_run - mnew);
    float p[16];
    float sum = 0.f;
    #pragma unroll
    for (int r = 0; r < 16; ++r) { p[r] = __expf(s[r] * 0.125f - mnew); sum += p[r]; }
    sum += __shfl_xor(sum, 32);
    l_run = l_run * corr + sum;
    m_run = mnew;
    #pragma unroll
    for (int r = 0; r < 16; ++r) { o0[r] *= corr; o1[r] *= corr; }

    // p -> bf16 B-fragments (2 K-slices of 16) via pack + permlane32_swap
    // lane (q,hi) needs k = hi*8+j (slice base +). own regs: w0=(k 4hi+0,1) w1=(k 4hi+2,3)
    // w2=(k 8+4hi+0,1) w3=(k 8+4hi+2,3). swap(w0,w2): .x=word0, .y=word2 (derivation in header)
    unsigned wds[8];
    #pragma unroll
    for (int g = 0; g < 2; ++g) {
      unsigned w0 = pack_bf16(p[g*8+0], p[g*8+1]);
      unsigned w1 = pack_bf16(p[g*8+2], p[g*8+3]);
      unsigned w2 = pack_bf16(p[g*8+4], p[g*8+5]);
      unsigned w3 = pack_bf16(p[g*8+6], p[g*8+7]);
#if __has_builtin(__builtin_amdgcn_permlane32_swap)
      u32x2 r02 = __builtin_amdgcn_permlane32_swap(w0, w2, false, false);
      u32x2 r13 = __builtin_amdgcn_permlane32_swap(w1, w3, false, false);
      wds[g*4+0] = r02.x; wds[g*4+1] = r13.x;
      wds[g*4+2] = r02.y; wds[g*4+3] = r13.y;
#else
      unsigned s0 = __shfl_xor(w0, 32), s1 = __shfl_xor(w1, 32);
      unsigned s2 = __shfl_xor(w2, 32), s3 = __shfl_xor(w3, 32);
      wds[g*4+0] = hi ? s2 : w0; wds[g*4+1] = hi ? s3 : w1;
      wds[g*4+2] = hi ? w2 : s0; wds[g*4+3] = hi ? w3 : s1;
#endif
    }
    union { unsigned u[4]; bf16x8 v; } pb0, pb1;
    pb0.u[0]=wds[0]; pb0.u[1]=wds[1]; pb0.u[2]=wds[2]; pb0.u[3]=wds[3];
    pb1.u[0]=wds[4]; pb1.u[1]=wds[5]; pb1.u[2]=wds[6]; pb1.u[3]=wds[7];

    // PV: O^T[d][q] += V^T-slice * P-slice
    o0 = __builtin_amdgcn_mfma_f32_32x32x16_bf16(vf00, pb0.v, o0, 0, 0, 0);
    o1 = __builtin_amdgcn_mfma_f32_32x32x16_bf16(vf10, pb0.v, o1, 0, 0, 0);
    o0 = __builtin_amdgcn_mfma_f32_32x32x16_bf16(vf01, pb1.v, o0, 0, 0, 0);
    o1 = __builtin_amdgcn_mfma_f32_32x32x16_bf16(vf11, pb1.v, o1, 0, 0, 0);
  }

  // epilogue: O^T reg r -> d=(r&3)+8*(r>>2)+4*hi (+32 for o1), q=l31
  float inv = 1.f / l_run;
  const int b = bh >> 4, h = bh & 15;
  const int q = q0 + l31;
  size_t rowbase = ((size_t)(b * SEQ + q)) * HIDDEN + h * 64;
  #pragma unroll
  for (int g = 0; g < 4; ++g) {
    us4 st0, st1;
    st0.x = f2b(o0[4*g+0] * inv); st0.y = f2b(o0[4*g+1] * inv);
    st0.z = f2b(o0[4*g+2] * inv); st0.w = f2b(o0[4*g+3] * inv);
    st1.x = f2b(o1[4*g+0] * inv); st1.y = f2b(o1[4*g+1] * inv);
    st1.z = f2b(o1[4*g+2] * inv); st1.w = f2b(o1[4*g+3] * inv);
    int d0 = g * 8 + hi * 4;
    *(us4*)(ctx + rowbase + d0)      = st0;
    *(us4*)(ctx + rowbase + 32 + d0) = st1;
  }
}

// ---------------- residual + LayerNorm ----------------
__global__ __launch_bounds__(256)
void k_ln(const float* __restrict__ a, const float* __restrict__ b,
          const float* __restrict__ gamma, const float* __restrict__ beta,
          float* __restrict__ outf, unsigned short* __restrict__ outb) {
  int row = blockIdx.x;
  int tid = threadIdx.x;
  const float4* A = (const float4*)(a + (size_t)row * HIDDEN);
  const float4* B = (const float4*)(b + (size_t)row * HIDDEN);
  float4 va = A[tid], vb = B[tid];
  float x0 = va.x + vb.x, x1 = va.y + vb.y, x2 = va.z + vb.z, x3 = va.w + vb.w;
  float sum = x0 + x1 + x2 + x3;
  float sq = x0 * x0 + x1 * x1 + x2 * x2 + x3 * x3;
  #pragma unroll
  for (int d = 1; d < 64; d <<= 1) { sum += __shfl_xor(sum, d); sq += __shfl_xor(sq, d); }
  __shared__ float red[8];
  if ((tid & 63) == 0) { red[(tid >> 6) * 2] = sum; red[(tid >> 6) * 2 + 1] = sq; }
  __syncthreads();
  sum = red[0] + red[2] + red[4] + red[6];
  sq  = red[1] + red[3] + red[5] + red[7];
  float mu = sum * (1.f / HIDDEN);
  float var = sq * (1.f / HIDDEN) - mu * mu;
  float rs = rsqrtf(var + 1e-5f);
  float4 g = ((const float4*)gamma)[tid];
  float4 be = ((const float4*)beta)[tid];
  float y0 = (x0 - mu) * rs * g.x + be.x;
  float y1 = (x1 - mu) * rs * g.y + be.y;
  float y2 = (x2 - mu) * rs * g.z + be.z;
  float y3 = (x3 - mu) * rs * g.w + be.w;
  if (outf) { float4 o; o.x = y0; o.y = y1; o.z = y2; o.w = y3; ((float4*)(outf + (size_t)row * HIDDEN))[tid] = o; }
  if (outb) { us4 o; o.x = f2b(y0); o.y = f2b(y1); o.z = f2b(y2); o.w = f2b(y3); ((us4*)(outb + (size_t)row * HIDDEN))[tid] = o; }
}

// ---------------- workspace layout (bytes) ----------------
// total required: 176,160,768 (168 MiB)
#define OFF_XB   ((size_t)0)            // x bf16 (16.78MB); reused as ln1_bf16
#define OFF_WQT  ((size_t)16777216)
#define OFF_WKT  ((size_t)18874368)
#define OFF_WVT  ((size_t)20971520)
#define OFF_WOT  ((size_t)23068672)
#define OFF_W1T  ((size_t)25165824)
#define OFF_W2T  ((size_t)33554432)
#define OFF_Q    ((size_t)41943040)     // Q; later overlaid by ff1 (spans Q..VT)
#define OFF_K    ((size_t)58720256)
#define OFF_V    ((size_t)75497472)     // V; reused as ctx
#define OFF_VT   ((size_t)92274688)
#define OFF_AO   ((size_t)109051904)    // attn proj out f32; reused as ff2 f32
#define OFF_LN1F ((size_t)142606336)

extern "C" void kernel_launch(void* const* d_in, const int* in_sizes, int n_in,
                              void* d_out, int out_size, void* d_ws, size_t ws_size,
                              hipStream_t stream) {
  const float* x   = (const float*)d_in[0];
  const float* Wq  = (const float*)d_in[1];
  const float* bq  = (const float*)d_in[2];
  const float* Wk  = (const float*)d_in[3];
  const float* bk  = (const float*)d_in[4];
  const float* Wv  = (const float*)d_in[5];
  const float* bv  = (const float*)d_in[6];
  const float* Wo  = (const float*)d_in[7];
  const float* bo  = (const float*)d_in[8];
  const float* W1  = (const float*)d_in[9];
  const float* b1  = (const float*)d_in[10];
  const float* W2  = (const float*)d_in[11];
  const float* b2  = (const float*)d_in[12];
  const float* g1  = (const float*)d_in[13];
  const float* be1 = (const float*)d_in[14];
  const float* g2  = (const float*)d_in[15];
  const float* be2 = (const float*)d_in[16];

  char* ws = (char*)d_ws;
  unsigned short* xb   = (unsigned short*)(ws + OFF_XB);
  unsigned short* wqT  = (unsigned short*)(ws + OFF_WQT);
  unsigned short* wkT  = (unsigned short*)(ws + OFF_WKT);
  unsigned short* wvT  = (unsigned short*)(ws + OFF_WVT);
  unsigned short* woT  = (unsigned short*)(ws + OFF_WOT);
  unsigned short* w1T  = (unsigned short*)(ws + OFF_W1T);
  unsigned short* w2T  = (unsigned short*)(ws + OFF_W2T);
  unsigned short* Qb   = (unsigned short*)(ws + OFF_Q);
  unsigned short* Kb   = (unsigned short*)(ws + OFF_K);
  unsigned short* Vb   = (unsigned short*)(ws + OFF_V);
  unsigned short* VTb  = (unsigned short*)(ws + OFF_VT);
  unsigned short* ctx  = (unsigned short*)(ws + OFF_V);    // reuse V
  float*          ao   = (float*)(ws + OFF_AO);
  float*          ln1f = (float*)(ws + OFF_LN1F);
  unsigned short* ln1b = (unsigned short*)(ws + OFF_XB);   // reuse xb
  unsigned short* ff1  = (unsigned short*)(ws + OFF_Q);    // reuse Q..VT span
  float*          ff2  = (float*)(ws + OFF_AO);            // reuse ao

  // 1. x -> bf16
  k_cvt<<<2048, 256, 0, stream>>>(x, xb, NTOK * HIDDEN / 4);

  // 2. weight transposes
  k_transcvt<<<dim3(16, 16), 256, 0, stream>>>(Wq, wqT, 1024, 1024);
  k_transcvt<<<dim3(16, 16), 256, 0, stream>>>(Wk, wkT, 1024, 1024);
  k_transcvt<<<dim3(16, 16), 256, 0, stream>>>(Wv, wvT, 1024, 1024);
  k_transcvt<<<dim3(16, 16), 256, 0, stream>>>(Wo, woT, 1024, 1024);
  k_transcvt<<<dim3(16, 64), 256, 0, stream>>>(W1, w1T, 1024, 4096);
  k_transcvt<<<dim3(64, 16), 256, 0, stream>>>(W2, w2T, 4096, 1024);

  // 3. QKV projections (scatter to [b,h,s,d])
  k_gemm<0><<<dim3(64, 8), 256, 0, stream>>>(xb, wqT, bq, Qb, NTOK, HIDDEN, HIDDEN);
  k_gemm<0><<<dim3(64, 8), 256, 0, stream>>>(xb, wkT, bk, Kb, NTOK, HIDDEN, HIDDEN);
  k_gemm<0><<<dim3(64, 8), 256, 0, stream>>>(xb, wvT, bv, Vb, NTOK, HIDDEN, HIDDEN);

  // 4. V -> VT
  k_vtrans<<<2048, 256, 0, stream>>>(Vb, VTb);

  // 5. attention -> ctx [b,s,h*64+d] bf16
  k_attn<<<1024, 256, 0, stream>>>(Qb, Kb, VTb, ctx);

  // 6. output projection -> fp32
  k_gemm<1><<<dim3(64, 8), 256, 0, stream>>>(ctx, woT, bo, ao, NTOK, HIDDEN, HIDDEN);

  // 7. LN1 (x + attn_out)
  k_ln<<<NTOK, 256, 0, stream>>>(x, ao, g1, be1, ln1f, ln1b);

  // 8. FFN1 + GELU -> bf16
  k_gemm<2><<<dim3(64, 32), 256, 0, stream>>>(ln1b, w1T, b1, ff1, NTOK, DFF, HIDDEN);

  // 9. FFN2 -> fp32
  k_gemm<1><<<dim3(64, 8), 256, 0, stream>>>(ff1, w2T, b2, ff2, NTOK, HIDDEN, DFF);

  // 10. LN2 -> d_out
  k_ln<<<NTOK, 256, 0, stream>>>(ln1f, ff2, g2, be2, (float*)d_out, nullptr);
}